// Round 1
// baseline (165.849 us; speedup 1.0000x reference)
//
#include <hip/hip_runtime.h>
#include <math.h>

// ws layout (floats):
// [0..255]   per-block raw max partials
// [256..511] per-block filtered min (-inf -> +inf) partials
// [512..767] per-block raw min partials
// [768]      filled value (for -inf replacement)
// [769]      1/(Cmax*EPS)
#define WS_MAX   0
#define WS_FMIN  256
#define WS_RMIN  512
#define WS_CONST 768

__device__ __forceinline__ float wred_max(float x){
  #pragma unroll
  for (int m = 32; m; m >>= 1) x = fmaxf(x, __shfl_xor(x, m, 64));
  return x;
}
__device__ __forceinline__ float wred_min(float x){
  #pragma unroll
  for (int m = 32; m; m >>= 1) x = fminf(x, __shfl_xor(x, m, 64));
  return x;
}
__device__ __forceinline__ float wred_sum(float x){
  #pragma unroll
  for (int m = 32; m; m >>= 1) x += __shfl_xor(x, m, 64);
  return x;
}

// Pass 1: per-block {raw max, filtered min, raw min} over all scores.
__global__ __launch_bounds__(256) void k_minmax(const float4* __restrict__ s4,
                                                int n4, float* __restrict__ ws){
  int tid = blockIdx.x * 256 + threadIdx.x;
  float mx = -INFINITY, fmn = INFINITY, rmn = INFINITY;
  for (int i = tid; i < n4; i += 256 * 256){
    float4 v = s4[i];
    float c[4] = {v.x, v.y, v.z, v.w};
    #pragma unroll
    for (int j = 0; j < 4; ++j){
      float s = c[j];
      mx  = fmaxf(mx, s);
      rmn = fminf(rmn, s);
      fmn = fminf(fmn, (s == -INFINITY) ? INFINITY : s);
    }
  }
  mx = wred_max(mx); fmn = wred_min(fmn); rmn = wred_min(rmn);
  __shared__ float sm[12];
  int w = threadIdx.x >> 6;
  if ((threadIdx.x & 63) == 0){ sm[w] = mx; sm[4 + w] = fmn; sm[8 + w] = rmn; }
  __syncthreads();
  if (threadIdx.x == 0){
    float a = fmaxf(fmaxf(sm[0], sm[1]), fmaxf(sm[2], sm[3]));
    float b = fminf(fminf(sm[4], sm[5]), fminf(sm[6], sm[7]));
    float c2 = fminf(fminf(sm[8], sm[9]), fminf(sm[10], sm[11]));
    ws[WS_MAX  + blockIdx.x] = a;
    ws[WS_FMIN + blockIdx.x] = b;
    ws[WS_RMIN + blockIdx.x] = c2;
  }
}

// Pass 2: fold 256 partials -> filled value and 1/(Cmax*EPS).
// Cmax = max over data of max(s^2,(s-1)^2); convex => attained at extreme
// data points {lo, hi}.
__global__ __launch_bounds__(256) void k_finalize(float* __restrict__ ws){
  int t = threadIdx.x;
  float mx = ws[WS_MAX + t], fmn = ws[WS_FMIN + t], rmn = ws[WS_RMIN + t];
  mx = wred_max(mx); fmn = wred_min(fmn); rmn = wred_min(rmn);
  __shared__ float sm[12];
  int w = t >> 6;
  if ((t & 63) == 0){ sm[w] = mx; sm[4 + w] = fmn; sm[8 + w] = rmn; }
  __syncthreads();
  if (t == 0){
    float max_s = fmaxf(fmaxf(sm[0], sm[1]), fmaxf(sm[2], sm[3]));
    float min_s = fminf(fminf(sm[4], sm[5]), fminf(sm[6], sm[7]));
    float rmin  = fminf(fminf(sm[8], sm[9]), fminf(sm[10], sm[11]));
    float filled = min_s - (max_s - min_s);
    float lo = (rmin == -INFINITY) ? filled : min_s;
    float hi = max_s;
    float cmax = fmaxf(fmaxf(lo * lo, (lo - 1.f) * (lo - 1.f)),
                       fmaxf(hi * hi, (hi - 1.f) * (hi - 1.f)));
    ws[WS_CONST]     = filled;
    ws[WS_CONST + 1] = 1.0f / (cmax * 0.1f);
  }
}

// Pass 3: one wave per row. r_i = G1/G0 = exp((2s-1)/(Cmax*EPS)).
// Iteration: w_i = 1/(v0 + r_i*v1); v0 = K/sum(w); v1 = (n-K)/sum(r*w).
// Output: A_i = v0_final * w_i(v_prev)  (G0 and 1/n factors cancel exactly).
__global__ __launch_bounds__(256) void k_sinkhorn(const float* __restrict__ scores,
                                                  float* __restrict__ out,
                                                  const float* __restrict__ cons){
  const float filled = cons[0];
  const float inv_xc = cons[1];
  const int row  = blockIdx.x * 4 + (threadIdx.x >> 6);
  const int lane = threadIdx.x & 63;
  const float4* __restrict__ src = (const float4*)(scores + (size_t)row * 2048);

  float r[32];
  #pragma unroll
  for (int k = 0; k < 8; ++k){
    float4 v = src[k * 64 + lane];
    float c[4] = {v.x, v.y, v.z, v.w};
    #pragma unroll
    for (int j = 0; j < 4; ++j){
      float s = c[j];
      if (s == -INFINITY) s = filled;
      r[k * 4 + j] = expf((2.0f * s - 1.0f) * inv_xc);
    }
  }

  float v0 = 0.5f, v1 = 0.5f, v0p = 0.5f, v1p = 0.5f;
  for (int it = 0; it < 50; ++it){
    float sw0 = 0.f, sw1 = 0.f, sw2 = 0.f, sw3 = 0.f;
    float sr0 = 0.f, sr1 = 0.f, sr2 = 0.f, sr3 = 0.f;
    #pragma unroll
    for (int k = 0; k < 32; k += 4){
      float w0 = __builtin_amdgcn_rcpf(fmaf(r[k + 0], v1, v0));
      float w1 = __builtin_amdgcn_rcpf(fmaf(r[k + 1], v1, v0));
      float w2 = __builtin_amdgcn_rcpf(fmaf(r[k + 2], v1, v0));
      float w3 = __builtin_amdgcn_rcpf(fmaf(r[k + 3], v1, v0));
      sw0 += w0; sw1 += w1; sw2 += w2; sw3 += w3;
      sr0 = fmaf(r[k + 0], w0, sr0);
      sr1 = fmaf(r[k + 1], w1, sr1);
      sr2 = fmaf(r[k + 2], w2, sr2);
      sr3 = fmaf(r[k + 3], w3, sr3);
    }
    float sw = (sw0 + sw1) + (sw2 + sw3);
    float sr = (sr0 + sr1) + (sr2 + sr3);
    sw = wred_sum(sw);
    sr = wred_sum(sr);
    v0p = v0; v1p = v1;
    v0 = 64.0f   / sw;   // K / sum(w)         (K = 64)
    v1 = 1984.0f / sr;   // (n-K) / sum(r*w)   (n-K = 1984)
  }

  float4* __restrict__ dst = (float4*)(out + (size_t)row * 2048);
  #pragma unroll
  for (int k = 0; k < 8; ++k){
    float4 o;
    o.x = v0 * __builtin_amdgcn_rcpf(fmaf(r[k * 4 + 0], v1p, v0p));
    o.y = v0 * __builtin_amdgcn_rcpf(fmaf(r[k * 4 + 1], v1p, v0p));
    o.z = v0 * __builtin_amdgcn_rcpf(fmaf(r[k * 4 + 2], v1p, v0p));
    o.w = v0 * __builtin_amdgcn_rcpf(fmaf(r[k * 4 + 3], v1p, v0p));
    dst[k * 64 + lane] = o;
  }
}

extern "C" void kernel_launch(void* const* d_in, const int* in_sizes, int n_in,
                              void* d_out, int out_size, void* d_ws, size_t ws_size,
                              hipStream_t stream) {
  const float* scores = (const float*)d_in[0];
  float* out = (float*)d_out;
  float* ws  = (float*)d_ws;
  const int n4 = in_sizes[0] / 4;  // 2,097,152 float4s

  k_minmax  <<<256, 256, 0, stream>>>((const float4*)scores, n4, ws);
  k_finalize<<<1,   256, 0, stream>>>(ws);
  k_sinkhorn<<<1024, 256, 0, stream>>>(scores, out, ws + WS_CONST);
}

// Round 2
// 110.363 us; speedup vs baseline: 1.5028x; 1.5028x over previous
//
#include <hip/hip_runtime.h>
#include <math.h>

// ws layout (floats):
// [0..1024)      per-block raw max partials
// [1024..2048)   per-block filtered min (-inf -> +inf) partials
// [2048..3072)   per-block raw min partials
// [3072]         filled value (-inf replacement)
// [3073]         cA = 2*log2(e)/(Cmax*EPS)   (r = exp2(s*cA + cB))
// [3074]         cB = -log2(e)/(Cmax*EPS)
#define NB_MM   1024
#define WS_MAX  0
#define WS_FMIN 1024
#define WS_RMIN 2048
#define WS_CONST 3072

__device__ __forceinline__ float wred_max(float x){
  #pragma unroll
  for (int m = 32; m; m >>= 1) x = fmaxf(x, __shfl_xor(x, m, 64));
  return x;
}
__device__ __forceinline__ float wred_min(float x){
  #pragma unroll
  for (int m = 32; m; m >>= 1) x = fminf(x, __shfl_xor(x, m, 64));
  return x;
}
__device__ __forceinline__ float wred_sum(float x){
  #pragma unroll
  for (int m = 32; m; m >>= 1) x += __shfl_xor(x, m, 64);
  return x;
}

// Pass 1: per-block {raw max, filtered min, raw min} over all scores.
__global__ __launch_bounds__(256) void k_minmax(const float4* __restrict__ s4,
                                                int n4, float* __restrict__ ws){
  int tid = blockIdx.x * 256 + threadIdx.x;
  float mx = -INFINITY, fmn = INFINITY, rmn = INFINITY;
  for (int i = tid; i < n4; i += NB_MM * 256){
    float4 v = s4[i];
    float c[4] = {v.x, v.y, v.z, v.w};
    #pragma unroll
    for (int j = 0; j < 4; ++j){
      float s = c[j];
      mx  = fmaxf(mx, s);
      rmn = fminf(rmn, s);
      fmn = fminf(fmn, (s == -INFINITY) ? INFINITY : s);
    }
  }
  mx = wred_max(mx); fmn = wred_min(fmn); rmn = wred_min(rmn);
  __shared__ float sm[12];
  int w = threadIdx.x >> 6;
  if ((threadIdx.x & 63) == 0){ sm[w] = mx; sm[4 + w] = fmn; sm[8 + w] = rmn; }
  __syncthreads();
  if (threadIdx.x == 0){
    ws[WS_MAX  + blockIdx.x] = fmaxf(fmaxf(sm[0], sm[1]), fmaxf(sm[2], sm[3]));
    ws[WS_FMIN + blockIdx.x] = fminf(fminf(sm[4], sm[5]), fminf(sm[6], sm[7]));
    ws[WS_RMIN + blockIdx.x] = fminf(fminf(sm[8], sm[9]), fminf(sm[10], sm[11]));
  }
}

// Pass 2: fold partials -> filled value and exp2 coefficients.
// Cmax = max over data of max(s^2,(s-1)^2); convex => attained at extremes.
__global__ __launch_bounds__(256) void k_finalize(float* __restrict__ ws){
  int t = threadIdx.x;
  float mx = -INFINITY, fmn = INFINITY, rmn = INFINITY;
  #pragma unroll
  for (int j = 0; j < NB_MM / 256; ++j){
    mx  = fmaxf(mx,  ws[WS_MAX  + t + 256 * j]);
    fmn = fminf(fmn, ws[WS_FMIN + t + 256 * j]);
    rmn = fminf(rmn, ws[WS_RMIN + t + 256 * j]);
  }
  mx = wred_max(mx); fmn = wred_min(fmn); rmn = wred_min(rmn);
  __shared__ float sm[12];
  int w = t >> 6;
  if ((t & 63) == 0){ sm[w] = mx; sm[4 + w] = fmn; sm[8 + w] = rmn; }
  __syncthreads();
  if (t == 0){
    float max_s = fmaxf(fmaxf(sm[0], sm[1]), fmaxf(sm[2], sm[3]));
    float min_s = fminf(fminf(sm[4], sm[5]), fminf(sm[6], sm[7]));
    float rmin  = fminf(fminf(sm[8], sm[9]), fminf(sm[10], sm[11]));
    float filled = min_s - (max_s - min_s);
    float lo = (rmin == -INFINITY) ? filled : min_s;
    float hi = max_s;
    float cmax = fmaxf(fmaxf(lo * lo, (lo - 1.f) * (lo - 1.f)),
                       fmaxf(hi * hi, (hi - 1.f) * (hi - 1.f)));
    float invX = 1.0f / (cmax * 0.1f);           // 1/(Cmax*EPS)
    float c = 1.4426950408889634f * invX;        // log2(e)/(Cmax*EPS)
    ws[WS_CONST]     = filled;
    ws[WS_CONST + 1] = 2.0f * c;                 // cA
    ws[WS_CONST + 2] = -c;                       // cB
  }
}

// Pass 3: one wave per row.
// r_i = G1/G0 = exp2(s*cA + cB).  Scalar state t = v0/v1 (t0 = 1).
//   acc = sum_i 1/(t + r_i)   (4-way batched reciprocals)
//   P   = t*acc;  t' = t * (K/(n-K)) * (n-P)/P
// Output A_i = (K*t/P) * 1/(t + r_i) using the final iteration's (t,P).
__global__ __launch_bounds__(256) void k_sinkhorn(const float* __restrict__ scores,
                                                  float* __restrict__ out,
                                                  const float* __restrict__ cons){
  const float filled = cons[0];
  const float cA = cons[1], cB = cons[2];
  const int row  = blockIdx.x * 4 + (threadIdx.x >> 6);
  const int lane = threadIdx.x & 63;
  const float4* __restrict__ src = (const float4*)(scores + (size_t)row * 2048);

  float r[32];
  #pragma unroll
  for (int k = 0; k < 8; ++k){
    float4 v = src[k * 64 + lane];
    float c[4] = {v.x, v.y, v.z, v.w};
    #pragma unroll
    for (int j = 0; j < 4; ++j){
      float s = c[j];
      if (s == -INFINITY) s = filled;
      r[k * 4 + j] = __builtin_amdgcn_exp2f(fmaf(s, cA, cB));
    }
  }

  float t = 1.0f, P = 0.0f;
  int it = 0;
  while (true){
    float acc0 = 0.f, acc1 = 0.f;
    #pragma unroll
    for (int g = 0; g < 8; g += 2){
      {
        float a0 = t + r[4*g+0], a1 = t + r[4*g+1];
        float a2 = t + r[4*g+2], a3 = t + r[4*g+3];
        float m01 = a0 * a1, m23 = a2 * a3;
        float s01 = a0 + a1, s23 = a2 + a3;
        float num = fmaf(m01, s23, m23 * s01);
        float den = m01 * m23;
        acc0 = fmaf(num, __builtin_amdgcn_rcpf(den), acc0);
      }
      {
        float a0 = t + r[4*g+4], a1 = t + r[4*g+5];
        float a2 = t + r[4*g+6], a3 = t + r[4*g+7];
        float m01 = a0 * a1, m23 = a2 * a3;
        float s01 = a0 + a1, s23 = a2 + a3;
        float num = fmaf(m01, s23, m23 * s01);
        float den = m01 * m23;
        acc1 = fmaf(num, __builtin_amdgcn_rcpf(den), acc1);
      }
    }
    float acc = wred_sum(acc0 + acc1);
    P = t * acc;
    if (++it == 50) break;
    float tn = t * (2048.0f - P) * 0.0322580645161f * __builtin_amdgcn_rcpf(P);
    if (fabsf(tn - t) <= 1e-7f * t) break;   // converged: further ref iters are no-ops
    t = tn;
  }

  const float c0 = 64.0f * t * __builtin_amdgcn_rcpf(P);
  float4* __restrict__ dst = (float4*)(out + (size_t)row * 2048);
  #pragma unroll
  for (int k = 0; k < 8; ++k){
    float4 o;
    o.x = c0 * __builtin_amdgcn_rcpf(t + r[k * 4 + 0]);
    o.y = c0 * __builtin_amdgcn_rcpf(t + r[k * 4 + 1]);
    o.z = c0 * __builtin_amdgcn_rcpf(t + r[k * 4 + 2]);
    o.w = c0 * __builtin_amdgcn_rcpf(t + r[k * 4 + 3]);
    dst[k * 64 + lane] = o;
  }
}

extern "C" void kernel_launch(void* const* d_in, const int* in_sizes, int n_in,
                              void* d_out, int out_size, void* d_ws, size_t ws_size,
                              hipStream_t stream) {
  const float* scores = (const float*)d_in[0];
  float* out = (float*)d_out;
  float* ws  = (float*)d_ws;
  const int n4 = in_sizes[0] / 4;

  k_minmax  <<<NB_MM, 256, 0, stream>>>((const float4*)scores, n4, ws);
  k_finalize<<<1,     256, 0, stream>>>(ws);
  k_sinkhorn<<<1024,  256, 0, stream>>>(scores, out, ws + WS_CONST);
}